// Round 1
// baseline (178.267 us; speedup 1.0000x reference)
//
#include <hip/hip_runtime.h>

#define SRC_LEN 256
#define TRG_LEN 256
#define BATCH   32
#define HID     512
#define ATT     128
#define CSCALE  2.885390081777927f   // 2*log2(e): exp2(CSCALE*x) == exp(2x)
#define RSTR    68                   // padded LDS stride (floats) for row tile

// ---------------------------------------------------------------------------
// Fused projection kernel.
//  blocks [0,256):   encT[b][a][s] = CSCALE * sum_k enc_outs[s][b][k]*W_s[a][k]
//  blocks [256,512): decC[t][b][a] = CSCALE * (sum_k dec_out[t][b][k]*W_t[a][k] + b_t[a])
// Tile: 32 rows x 128 cols, K-chunk 64, 256 threads, thread-tile 4x4.
// W staged transposed in LDS with XOR swizzle to avoid transpose-write bank
// conflicts while keeping 16B-aligned ds_read_b128 on the read side.
// ---------------------------------------------------------------------------
__global__ __launch_bounds__(256) void proj_kernel(
    const float* __restrict__ dec_out, const float* __restrict__ enc_outs,
    const float* __restrict__ W_s, const float* __restrict__ W_t,
    const float* __restrict__ b_t,
    float* __restrict__ encT, float* __restrict__ decC)
{
    __shared__ float rowsL[32 * RSTR];
    __shared__ float wL[64 * 128];

    const int blk   = blockIdx.x;
    const bool isDec = (blk >= 256);
    const int r0    = (isDec ? blk - 256 : blk) * 32;   // row = (s or t)*32 + b
    const float* __restrict__ in = isDec ? dec_out : enc_outs;
    const float* __restrict__ W  = isDec ? W_t : W_s;

    const int tid = threadIdx.x;
    const int ct  = tid & 31;   // col group: a = ct*4 .. ct*4+3
    const int rt  = tid >> 5;   // row group: local rows rt*4 .. rt*4+3

    float acc[4][4];
    #pragma unroll
    for (int i = 0; i < 4; ++i)
        #pragma unroll
        for (int j = 0; j < 4; ++j) acc[i][j] = 0.0f;

    for (int k0 = 0; k0 < HID; k0 += 64) {
        // stage 32x64 row chunk: 512 float4, 2 per thread
        #pragma unroll
        for (int it = 0; it < 2; ++it) {
            int f = tid + it * 256;
            int i = f >> 4, kc = f & 15;
            float4 v = *(const float4*)(in + (size_t)(r0 + i) * HID + k0 + kc * 4);
            *(float4*)(rowsL + i * RSTR + kc * 4) = v;
        }
        // stage 128x64 W chunk, transposed + swizzled: 2048 float4, 8 per thread
        #pragma unroll
        for (int it = 0; it < 8; ++it) {
            int f = tid + it * 256;
            int a = f >> 4, kc = f & 15;
            float4 v = *(const float4*)(W + (size_t)a * HID + k0 + kc * 4);
            int sw = a ^ (4 * (kc & 7));        // g(k)=4*((k>>2)&7), k=kc*4+q
            wL[(kc * 4 + 0) * 128 + sw] = v.x;
            wL[(kc * 4 + 1) * 128 + sw] = v.y;
            wL[(kc * 4 + 2) * 128 + sw] = v.z;
            wL[(kc * 4 + 3) * 128 + sw] = v.w;
        }
        __syncthreads();

        #pragma unroll 4
        for (int k = 0; k < 64; ++k) {
            const int g = 4 * ((k >> 2) & 7);
            const float4 w = *(const float4*)(wL + k * 128 + ((ct * 4) ^ g));
            const float e0 = rowsL[(rt * 4 + 0) * RSTR + k];
            const float e1 = rowsL[(rt * 4 + 1) * RSTR + k];
            const float e2 = rowsL[(rt * 4 + 2) * RSTR + k];
            const float e3 = rowsL[(rt * 4 + 3) * RSTR + k];
            acc[0][0] = fmaf(e0, w.x, acc[0][0]);
            acc[0][1] = fmaf(e0, w.y, acc[0][1]);
            acc[0][2] = fmaf(e0, w.z, acc[0][2]);
            acc[0][3] = fmaf(e0, w.w, acc[0][3]);
            acc[1][0] = fmaf(e1, w.x, acc[1][0]);
            acc[1][1] = fmaf(e1, w.y, acc[1][1]);
            acc[1][2] = fmaf(e1, w.z, acc[1][2]);
            acc[1][3] = fmaf(e1, w.w, acc[1][3]);
            acc[2][0] = fmaf(e2, w.x, acc[2][0]);
            acc[2][1] = fmaf(e2, w.y, acc[2][1]);
            acc[2][2] = fmaf(e2, w.z, acc[2][2]);
            acc[2][3] = fmaf(e2, w.w, acc[2][3]);
            acc[3][0] = fmaf(e3, w.x, acc[3][0]);
            acc[3][1] = fmaf(e3, w.y, acc[3][1]);
            acc[3][2] = fmaf(e3, w.z, acc[3][2]);
            acc[3][3] = fmaf(e3, w.w, acc[3][3]);
        }
        __syncthreads();
    }

    if (!isDec) {
        // rows r0..r0+31 are s = blk, b = 0..31 (r = s*BATCH + b, r0 = blk*32)
        const int s = blk;
        #pragma unroll
        for (int rr = 0; rr < 4; ++rr) {
            const int b = rt * 4 + rr;
            #pragma unroll
            for (int cc = 0; cc < 4; ++cc) {
                const int a = ct * 4 + cc;
                encT[((size_t)b * ATT + a) * SRC_LEN + s] = acc[rr][cc] * CSCALE;
            }
        }
    } else {
        #pragma unroll
        for (int rr = 0; rr < 4; ++rr) {
            const int r = r0 + rt * 4 + rr;
            float4 o;
            o.x = (acc[rr][0] + b_t[ct * 4 + 0]) * CSCALE;
            o.y = (acc[rr][1] + b_t[ct * 4 + 1]) * CSCALE;
            o.z = (acc[rr][2] + b_t[ct * 4 + 2]) * CSCALE;
            o.w = (acc[rr][3] + b_t[ct * 4 + 3]) * CSCALE;
            *(float4*)(decC + (size_t)r * ATT + ct * 4) = o;
        }
    }
}

// ---------------------------------------------------------------------------
// Score kernel: scores[t][b][s] = sum_a v[a]*tanh(enc_att[s][b][a]+dec_att[t][b][a])
// With eS = CSCALE*enc_att, dS = CSCALE*dec_att (pre-scaled in proj):
//   tanh = 1 - 2/(1+exp2(eS+dS));  score = sumV - 2 * sum_a v[a]/(1+exp2(m))
// Block: one b, 8 consecutive t, lanes = s (256 threads). 268M exp+rcp total.
// ---------------------------------------------------------------------------
__global__ __launch_bounds__(256) void score_kernel(
    const float* __restrict__ encT, const float* __restrict__ decC,
    const float* __restrict__ v_a, float* __restrict__ out)
{
    __shared__ float dS[8 * ATT];
    __shared__ float vS[ATT];
    __shared__ float sumvS;

    const int tid = threadIdx.x;
    const int t0  = blockIdx.x * 8;
    const int b   = blockIdx.y;

    // stage dec tile (8 x 128) and v
    {
        const int tt = tid >> 5, a4 = (tid & 31) * 4;
        float4 v = *(const float4*)(decC + ((size_t)(t0 + tt) * BATCH + b) * ATT + a4);
        *(float4*)(dS + tt * ATT + a4) = v;
    }
    if (tid < 32) {
        float4 v = *(const float4*)(v_a + tid * 4);
        *(float4*)(vS + tid * 4) = v;
    }
    __syncthreads();
    if (tid < 64) {
        float x = vS[tid] + vS[tid + 64];
        #pragma unroll
        for (int o = 32; o > 0; o >>= 1) x += __shfl_down(x, o);
        if (tid == 0) sumvS = x;
    }
    __syncthreads();

    float acc[8];
    #pragma unroll
    for (int tt = 0; tt < 8; ++tt) acc[tt] = 0.0f;

    const float* __restrict__ ep = encT + (size_t)b * ATT * SRC_LEN + tid;

    #pragma unroll 2
    for (int a = 0; a < ATT; ++a) {
        const float e  = ep[a * SRC_LEN];     // coalesced: lane = s
        const float va = vS[a];
        #pragma unroll
        for (int tt = 0; tt < 8; ++tt) {
            const float m = e + dS[tt * ATT + a];
            const float p = __builtin_amdgcn_exp2f(m);
            const float r = __builtin_amdgcn_rcpf(1.0f + p);
            acc[tt] = fmaf(va, r, acc[tt]);
        }
    }

    const float sv = sumvS;
    #pragma unroll
    for (int tt = 0; tt < 8; ++tt) {
        out[((size_t)(t0 + tt) * BATCH + b) * SRC_LEN + tid] = sv - 2.0f * acc[tt];
    }
}

extern "C" void kernel_launch(void* const* d_in, const int* in_sizes, int n_in,
                              void* d_out, int out_size, void* d_ws, size_t ws_size,
                              hipStream_t stream) {
    const float* dec_out  = (const float*)d_in[0];
    const float* enc_outs = (const float*)d_in[1];
    const float* W_s      = (const float*)d_in[2];
    const float* W_t      = (const float*)d_in[3];
    const float* b_t      = (const float*)d_in[4];
    const float* v_a      = (const float*)d_in[5];
    float* out = (float*)d_out;

    float* encT = (float*)d_ws;                              // B*A*S  = 4 MB
    float* decC = encT + (size_t)BATCH * ATT * SRC_LEN;      // T*B*A  = 4 MB

    proj_kernel<<<512, 256, 0, stream>>>(dec_out, enc_outs, W_s, W_t, b_t, encT, decC);

    dim3 g3(TRG_LEN / 8, BATCH);
    score_kernel<<<g3, 256, 0, stream>>>(encT, decC, v_a, out);
}